// Round 4
// baseline (337.836 us; speedup 1.0000x reference)
//
#include <hip/hip_runtime.h>

#define BN 256   // batches
#define NN 256   // matrix dim
#define WL 8     // walk length

typedef __attribute__((ext_vector_type(4))) float f32x4;

// ---- f32 -> fp8 e4m3fn (OCP), RNE; manual fallback if builtin absent -------
__device__ inline unsigned f2e4m3(float x) {
  union { float f; unsigned u; } v; v.f = x;
  if (v.f <= 0.0f) return 0;                       // inputs are >= 0 here
  int e = (int)((v.u >> 23) & 0xff) - 127;
  if (e < -9) return 0;
  if (e < -6) {                                    // subnormal: q = RNE(x*512), 0..7
    int qi = (int)(x * 512.0f + 0.5f);
    return qi > 7 ? 7u : (unsigned)qi;
  }
  unsigned r = v.u + 0x7ffff + ((v.u >> 20) & 1);  // RNE to 3 mantissa bits
  e = (int)((r >> 23) & 0xff) - 127;
  unsigned m = (r >> 20) & 7;
  return (unsigned)(((e + 7) << 3) | m);           // e+7 in [1,15] for our range
}

__device__ inline unsigned pk4(float a, float b, float c, float d) {
#if __has_builtin(__builtin_amdgcn_cvt_pk_fp8_f32)
  int r = 0;
  r = __builtin_amdgcn_cvt_pk_fp8_f32(a, b, r, false);   // bytes 0,1
  r = __builtin_amdgcn_cvt_pk_fp8_f32(c, d, r, true);    // bytes 2,3
  return (unsigned)r;
#else
  return f2e4m3(a) | (f2e4m3(b) << 8) | (f2e4m3(c) << 16) | (f2e4m3(d) << 24);
#endif
}

// ---- fused kernel: one block per batch ------------------------------------
// LDS: S = 64*P, fp8 e4m3, row-major [256][256] with 8B-granule XOR swizzle:
//   byte(row, col) at row*256 + ((col>>3) ^ (row&31))*8 + (col&7)
// Swizzle makes both the A-frag ds_read_b64 (16 rows x 8 cols per quad) and
// the prep ds_write_b32 conflict-free with ZERO padding (exactly 64 KB).
__global__ __launch_bounds__(512, 2) void k_chain(const float* __restrict__ A,
                                                  float* __restrict__ out) {
  __shared__ unsigned char S[65536];
  int b  = blockIdx.x;
  int t  = threadIdx.x;
  int wi = t >> 6;                 // wave 0..7
  int l  = t & 63;
  int q  = l >> 4, l16 = l & 15;
  const float* Ab = A + (size_t)b * NN * NN;
  float* outb = out + (size_t)b * NN * WL;

  // ---- phase 1: prep. wave wi handles rows [32wi, 32wi+32), one row/pass.
  // lane l holds cols 4l..4l+3 of the row (float4 load, fully coalesced).
  for (int r0 = wi * 32; r0 < wi * 32 + 32; r0 += 8) {
    float4 rv[8];                                   // 8-deep load pipeline
    #pragma unroll
    for (int i = 0; i < 8; i++)
      rv[i] = *(const float4*)(Ab + (size_t)(r0 + i) * NN + l * 4);
    #pragma unroll
    for (int i = 0; i < 8; i++) {
      int row = r0 + i;                             // wave-uniform
      float t0 = rv[i].x > 0.3f ? rv[i].x : 0.0f;
      float t1 = rv[i].y > 0.3f ? rv[i].y : 0.0f;
      float t2 = rv[i].z > 0.3f ? rv[i].z : 0.0f;
      float t3 = rv[i].w > 0.3f ? rv[i].w : 0.0f;
      float s = (t0 + t1) + (t2 + t3);
      #pragma unroll
      for (int o = 32; o; o >>= 1) s += __shfl_xor(s, o);
      float dinv = s > 0.0f ? 1.0f / s : 0.0f;
      // out cols 0,1: identity and diag(P). col==row lives at lane row>>2.
      int rm = row & 3;                             // uniform
      float tv = rm == 0 ? t0 : rm == 1 ? t1 : rm == 2 ? t2 : t3;
      if (l == (row >> 2)) {
        outb[row * WL + 0] = 1.0f;
        outb[row * WL + 1] = tv * dinv;
      }
      float sc = dinv * 64.0f;                      // store S = 64*P
      unsigned pkd = pk4(t0 * sc, t1 * sc, t2 * sc, t3 * sc);
      unsigned addr = row * 256 + ((((unsigned)l >> 1) ^ (row & 31)) << 3) + ((l & 1) << 2);
      *(unsigned*)&S[addr] = pkd;
    }
  }
  __syncthreads();   // S complete; read-only hereafter -> no more barriers

  // ---- phase 2: initial B-frags. X1 = S, wave's column strip [32wi, +32).
  // B-frag(lnt,kt): lane (q,l16) holds X[k=32kt+8q+j][n=32wi+16lnt+l16], j=0..7
  long bcur[2][8];
  #pragma unroll
  for (int lnt = 0; lnt < 2; lnt++) {
    int n = wi * 32 + lnt * 16 + l16;
    int gcol = n >> 3, gbyte = n & 7;
    #pragma unroll
    for (int kt = 0; kt < 8; kt++) {
      unsigned d0 = 0, d1 = 0;
      #pragma unroll
      for (int j = 0; j < 4; j++) {
        int k0 = kt * 32 + q * 8 + j;
        int k1 = k0 + 4;
        unsigned b0 = S[k0 * 256 + ((gcol ^ (k0 & 31)) << 3) + gbyte];
        unsigned b1 = S[k1 * 256 + ((gcol ^ (k1 & 31)) << 3) + gbyte];
        d0 |= b0 << (8 * j);
        d1 |= b1 << (8 * j);
      }
      bcur[lnt][kt] = (long)(((unsigned long long)d1 << 32) | d0);
    }
  }

  // ---- phase 3: chain. D = S * X_k = 4096 * P^g. No barriers, no global I/O
  // except diag stores. A-frags re-read from LDS each step (A-reuse across
  // nt=2 in registers).
  const float invQ = 1.0f / 4096.0f;
  const float inv64 = 1.0f / 64.0f;
  for (int g = 2; g <= 7; g++) {
    f32x4 acc[16][2];
    #pragma unroll
    for (int mt = 0; mt < 16; mt++) {
      acc[mt][0] = (f32x4){0.f, 0.f, 0.f, 0.f};
      acc[mt][1] = (f32x4){0.f, 0.f, 0.f, 0.f};
    }
    #pragma unroll
    for (int kt = 0; kt < 8; kt++) {
      long bf0 = bcur[0][kt], bf1 = bcur[1][kt];
      #pragma unroll
      for (int mt = 0; mt < 16; mt++) {
        int row = 16 * mt + l16;
        int phys = (4 * kt + q) ^ (row & 31);
        long a = *(const long*)&S[row * 256 + phys * 8];
        acc[mt][0] = __builtin_amdgcn_mfma_f32_16x16x32_fp8_fp8(a, bf0, acc[mt][0], 0, 0, 0);
        acc[mt][1] = __builtin_amdgcn_mfma_f32_16x16x32_fp8_fp8(a, bf1, acc[mt][1], 0, 0, 0);
      }
    }
    // diag(P^g): C layout col=l16, row=4q+r; diagonal tiles are mt=2wi+lnt.
    if ((l16 >> 2) == q) {
      int r = l16 & 3;
      #pragma unroll
      for (int lnt = 0; lnt < 2; lnt++) {
        int i = 16 * (2 * wi + lnt) + l16;
        float dv = lnt == 0 ? acc[2 * wi][0][r] : acc[2 * wi + 1][1][r];
        outb[i * WL + g] = dv * invQ;
      }
    }
    if (g == 7) break;
    // transform: acc (C layout) -> next B-frags (X_{g} = acc/64), in-register.
    // pk[mt][lnt] = 4 fp8 = rows {4*quad..+3} of tile mt, col l16.
    unsigned pk[16][2];
    #pragma unroll
    for (int mt = 0; mt < 16; mt++)
      #pragma unroll
      for (int lnt = 0; lnt < 2; lnt++)
        pk[mt][lnt] = pk4(acc[mt][lnt][0] * inv64, acc[mt][lnt][1] * inv64,
                          acc[mt][lnt][2] * inv64, acc[mt][lnt][3] * inv64);
    // B-frag(lnt,kt) dword d: rows k=32kt+8q+4d..+3 of col n ->
    //   src lane (quad_c = 2(q&1)+d, same l16), reg set MT = 2kt + (q>>1).
    int src0 = ((2 * (q & 1) + 0) << 4) | l16;
    int src1 = ((2 * (q & 1) + 1) << 4) | l16;
    int hiq = q >> 1;
    #pragma unroll
    for (int lnt = 0; lnt < 2; lnt++)
      #pragma unroll
      for (int kt = 0; kt < 8; kt++) {
        unsigned lo0 = (unsigned)__shfl((int)pk[2 * kt][lnt], src0);
        unsigned hi0 = (unsigned)__shfl((int)pk[2 * kt + 1][lnt], src0);
        unsigned lo1 = (unsigned)__shfl((int)pk[2 * kt][lnt], src1);
        unsigned hi1 = (unsigned)__shfl((int)pk[2 * kt + 1][lnt], src1);
        unsigned d0 = hiq ? hi0 : lo0;
        unsigned d1 = hiq ? hi1 : lo1;
        bcur[lnt][kt] = (long)(((unsigned long long)d1 << 32) | d0);
      }
  }
}

extern "C" void kernel_launch(void* const* d_in, const int* in_sizes, int n_in,
                              void* d_out, int out_size, void* d_ws, size_t ws_size,
                              hipStream_t stream) {
  const float* A = (const float*)d_in[0];
  float* out = (float*)d_out;
  k_chain<<<BN, 512, 0, stream>>>(A, out);
}

// Round 5
// 203.864 us; speedup vs baseline: 1.6572x; 1.6572x over previous
//
#include <hip/hip_runtime.h>

#define BN 256   // batches
#define NN 256   // matrix dim
#define WL 8     // walk length

typedef __attribute__((ext_vector_type(4))) float f32x4;
typedef unsigned long long ull;

// ---- f32 -> fp8 e4m3fn (OCP), RNE; manual fallback if builtin absent -------
__device__ inline unsigned f2e4m3(float x) {
  union { float f; unsigned u; } v; v.f = x;
  if (v.f <= 0.0f) return 0;                       // inputs are >= 0 here
  int e = (int)((v.u >> 23) & 0xff) - 127;
  if (e < -9) return 0;
  if (e < -6) {                                    // subnormal: q = RNE(x*512)
    int qi = (int)(x * 512.0f + 0.5f);
    return qi > 7 ? 7u : (unsigned)qi;
  }
  unsigned r = v.u + 0x7ffff + ((v.u >> 20) & 1);  // RNE to 3 mantissa bits
  e = (int)((r >> 23) & 0xff) - 127;
  unsigned m = (r >> 20) & 7;
  return (unsigned)(((e + 7) << 3) | m);
}

__device__ inline unsigned pk4(float a, float b, float c, float d) {
#if __has_builtin(__builtin_amdgcn_cvt_pk_fp8_f32)
  int r = 0;
  r = __builtin_amdgcn_cvt_pk_fp8_f32(a, b, r, false);   // bytes 0,1
  r = __builtin_amdgcn_cvt_pk_fp8_f32(c, d, r, true);    // bytes 2,3
  return (unsigned)r;
#else
  return f2e4m3(a) | (f2e4m3(b) << 8) | (f2e4m3(c) << 16) | (f2e4m3(d) << 24);
#endif
}

// ---- fused kernel: one block (8 waves) per batch ---------------------------
// LDS: S = 64*P, fp8 e4m3, row-major with 8B-granule XOR swizzle:
//   byte(row,col) at row*256 + ((col>>3) ^ (row&31))*8 + (col&7)
// A-frag ds_read_b64 and prep ds_write_b32 are conflict-free; exactly 64 KB.
//
// Chain: bcur holds 64*P^{g-1} as fp8 B-frags (g=1: identity, unscaled).
// Step g: acc = S*bcur = 4096*P^g (64*P for g=1); diag = acc/4096;
// bnext = fp8(acc/64) (acc*1 for g=1). mt-PAIR loop keeps live regs ~100:
// bnext[lnt][pt] depends only on acc tiles {2pt, 2pt+1}, so each pair's acc
// retires immediately into its B-frag via 8 shuffles. No spills, no barriers
// after the first, no global traffic except in/out.
__global__ __launch_bounds__(512, 2) void k_chain(const float* __restrict__ A,
                                                  float* __restrict__ out) {
  __shared__ unsigned char S[65536];
  int b  = blockIdx.x;
  int t  = threadIdx.x;
  int wi = t >> 6;                 // wave 0..7
  int l  = t & 63;
  int q  = l >> 4, l16 = l & 15;
  const float* Ab = A + (size_t)b * NN * NN;
  float* outb = out + (size_t)b * NN * WL;

  // ---- phase 1: prep. wave wi handles rows [32wi, 32wi+32).
  for (int r0 = wi * 32; r0 < wi * 32 + 32; r0 += 8) {
    float4 rv[8];                                   // 8-deep load pipeline
    #pragma unroll
    for (int i = 0; i < 8; i++)
      rv[i] = *(const float4*)(Ab + (size_t)(r0 + i) * NN + l * 4);
    #pragma unroll
    for (int i = 0; i < 8; i++) {
      int row = r0 + i;                             // wave-uniform
      float t0 = rv[i].x > 0.3f ? rv[i].x : 0.0f;
      float t1 = rv[i].y > 0.3f ? rv[i].y : 0.0f;
      float t2 = rv[i].z > 0.3f ? rv[i].z : 0.0f;
      float t3 = rv[i].w > 0.3f ? rv[i].w : 0.0f;
      float s = (t0 + t1) + (t2 + t3);
      #pragma unroll
      for (int o = 32; o; o >>= 1) s += __shfl_xor(s, o);
      float dinv = s > 0.0f ? 1.0f / s : 0.0f;
      int rm = row & 3;                             // uniform
      float tv = rm == 0 ? t0 : rm == 1 ? t1 : rm == 2 ? t2 : t3;
      if (l == (row >> 2)) {
        outb[row * WL + 0] = 1.0f;
        outb[row * WL + 1] = tv * dinv;             // diag(P), exact f32
      }
      float sc = dinv * 64.0f;                      // store S = 64*P
      unsigned pkd = pk4(t0 * sc, t1 * sc, t2 * sc, t3 * sc);
      unsigned addr = row * 256 + ((((unsigned)l >> 1) ^ (row & 31)) << 3) + ((l & 1) << 2);
      *(unsigned*)&S[addr] = pkd;
    }
  }
  __syncthreads();   // S complete; read-only hereafter

  // ---- phase 2: identity B-frags (X0 = I). B[k][n]=1 iff k==n,
  // n = 32wi+16lnt+l16, k = 32kt+8q+j  ->  kt==wi, q==2lnt+(l16>>3), j=l16&7.
  long bcur[2][8], bnext[2][8];
  #pragma unroll
  for (int lnt = 0; lnt < 2; lnt++)
    #pragma unroll
    for (int kt = 0; kt < 8; kt++)
      bcur[lnt][kt] = (kt == wi && q == 2 * lnt + (l16 >> 3))
                        ? (long)(0x38ull << (8 * (l16 & 7)))   // e4m3 1.0
                        : 0L;

  // ---- phase 3: chain, mt-pair structured.
  const float invQ = 1.0f / 4096.0f;
  const float inv64 = 1.0f / 64.0f;
  for (int g = 1; g <= 7; g++) {
    float osc = (g == 1) ? 1.0f : inv64;            // bnext scale
    #pragma unroll
    for (int pt = 0; pt < 8; pt++) {                // tiles mt = 2pt, 2pt+1
      f32x4 acc[2][2];
      acc[0][0] = (f32x4){0.f, 0.f, 0.f, 0.f};
      acc[0][1] = (f32x4){0.f, 0.f, 0.f, 0.f};
      acc[1][0] = (f32x4){0.f, 0.f, 0.f, 0.f};
      acc[1][1] = (f32x4){0.f, 0.f, 0.f, 0.f};
      int row0 = 32 * pt + l16;
      int row1 = row0 + 16;
      #pragma unroll
      for (int kt = 0; kt < 8; kt++) {
        long a0 = *(const long*)&S[row0 * 256 + (((4 * kt + q) ^ (row0 & 31)) << 3)];
        long a1 = *(const long*)&S[row1 * 256 + (((4 * kt + q) ^ (row1 & 31)) << 3)];
        acc[0][0] = __builtin_amdgcn_mfma_f32_16x16x32_fp8_fp8(a0, bcur[0][kt], acc[0][0], 0, 0, 0);
        acc[0][1] = __builtin_amdgcn_mfma_f32_16x16x32_fp8_fp8(a0, bcur[1][kt], acc[0][1], 0, 0, 0);
        acc[1][0] = __builtin_amdgcn_mfma_f32_16x16x32_fp8_fp8(a1, bcur[0][kt], acc[1][0], 0, 0, 0);
        acc[1][1] = __builtin_amdgcn_mfma_f32_16x16x32_fp8_fp8(a1, bcur[1][kt], acc[1][1], 0, 0, 0);
      }
      // diag(P^g): C layout col=l16, row=4q+r. Diagonal tiles: pt==wi,
      // tile 2pt <-> lnt=0 (acc[0][0]), tile 2pt+1 <-> lnt=1 (acc[1][1]).
      if (g >= 2 && pt == wi && (l16 >> 2) == q) {
        int r = l16 & 3;
        outb[(32 * pt + l16) * WL + g]      = acc[0][0][r] * invQ;
        outb[(32 * pt + 16 + l16) * WL + g] = acc[1][1][r] * invQ;
      }
      if (g < 7) {
        // acc -> bnext[.][pt]: frag dword d, quad q needs tile 2pt+(q>>1),
        // source quad_c = 2(q&1)+d, same l16.
        unsigned pkv[2][2];
        #pragma unroll
        for (int mtl = 0; mtl < 2; mtl++)
          #pragma unroll
          for (int lnt = 0; lnt < 2; lnt++)
            pkv[mtl][lnt] = pk4(acc[mtl][lnt][0] * osc, acc[mtl][lnt][1] * osc,
                                acc[mtl][lnt][2] * osc, acc[mtl][lnt][3] * osc);
        int src0 = ((q & 1) << 5) | l16;   // quad_c = 2(q&1)
        int src1 = src0 + 16;              // quad_c = 2(q&1)+1
        int hiq = q >> 1;
        #pragma unroll
        for (int lnt = 0; lnt < 2; lnt++) {
          unsigned lo0 = (unsigned)__shfl((int)pkv[0][lnt], src0);
          unsigned hi0 = (unsigned)__shfl((int)pkv[1][lnt], src0);
          unsigned lo1 = (unsigned)__shfl((int)pkv[0][lnt], src1);
          unsigned hi1 = (unsigned)__shfl((int)pkv[1][lnt], src1);
          unsigned d0 = hiq ? hi0 : lo0;
          unsigned d1 = hiq ? hi1 : lo1;
          bnext[lnt][pt] = (long)(((ull)d1 << 32) | d0);
        }
      }
    }
    if (g < 7) {
      #pragma unroll
      for (int lnt = 0; lnt < 2; lnt++)
        #pragma unroll
        for (int kt = 0; kt < 8; kt++)
          bcur[lnt][kt] = bnext[lnt][kt];
    }
  }
}

extern "C" void kernel_launch(void* const* d_in, const int* in_sizes, int n_in,
                              void* d_out, int out_size, void* d_ws, size_t ws_size,
                              hipStream_t stream) {
  const float* A = (const float*)d_in[0];
  float* out = (float*)d_out;
  k_chain<<<BN, 512, 0, stream>>>(A, out);
}